// Round 11
// baseline (340.716 us; speedup 1.0000x reference)
//
#include <hip/hip_runtime.h>
#include <hip/hip_bf16.h>

#define B_   64
#define T_   512
#define N_   14
#define F_   16
#define H_   128
#define G4_  512
#define TCH  64     // timesteps staged per LDS chunk
#define MBLK 2      // sequences per block
#define NBLK 448    // 2 blocks per CU -> independent barrier domains

typedef __attribute__((ext_vector_type(8))) short bfrag;  // 8 bf16
typedef __attribute__((ext_vector_type(4))) float facc;   // fp32 acc
typedef __attribute__((ext_vector_type(4))) int   v4i;    // i8x16 / i32x4

#define L2E   1.4426950408889634f
#define L2E2  2.8853900817779268f

// LDS byte offsets
#define SX   0      // x: [64 tl][2 seq][32 k] bf16 (k>=16 zero) = 8 KB
#define SH   8192   // h8: [2 parity][8 kslice][2 group][16B] = 512 B
#define LDSZ 8704

__device__ __forceinline__ short f2bf(float f) {
    unsigned u = __builtin_bit_cast(unsigned, f);
    return (short)((u + 0x7FFFu + ((u >> 16) & 1u)) >> 16);
}
__device__ __forceinline__ float bf2f(unsigned short s) {
    return __builtin_bit_cast(float, (unsigned)s << 16);
}
__device__ __forceinline__ unsigned cvt_pk_bf16(float a, float b) {
    unsigned r;
    asm("v_cvt_pk_bf16_f32 %0, %1, %2" : "=v"(r) : "v"(a), "v"(b));
    return r;
}
// i8 MFMA (validated rounds 6-10)
__device__ __forceinline__ v4i mfma_i8(v4i a, v4i b, v4i c) {
    v4i d;
    asm("v_mfma_i32_16x16x64_i8 %0, %1, %2, %3"
        : "=&v"(d) : "v"(a), "v"(b), "v"(c));
    return d;
}
// lgkm-only barrier: global prefetch loads stay in flight across barriers.
__device__ __forceinline__ void bar() {
    asm volatile("s_waitcnt lgkmcnt(0)" ::: "memory");
    __builtin_amdgcn_s_barrier();
    asm volatile("" ::: "memory");
}

// ---------------------------------------------------------------------------
// prep1: per-gate-row max of W_hh -> i8 scale; fused biases; log2e pre-scale
// (2x for the g-gate section) so the epilogue uses native exp2.
// ---------------------------------------------------------------------------
__global__ void prep1_kernel(const float* __restrict__ W_hh,
                             const float* __restrict__ b_ih, const float* __restrict__ b_hh,
                             float* __restrict__ inv127, float* __restrict__ sw,
                             float* __restrict__ bias) {
    const int g = threadIdx.x;            // 0..511
    float mx = 0.0f;
    for (int k = 0; k < H_; ++k) mx = fmaxf(mx, fabsf(W_hh[g * H_ + k]));
    const float sc = (g >= 256 && g < 384) ? L2E2 : L2E;
    inv127[g] = 127.0f / mx;
    sw[g]     = mx * sc * (1.0f / 16129.0f);   // mx/127 * 1/127 * log2e-scale
    bias[g]   = (b_ih[g] + b_hh[g]) * sc;
}

// ---------------------------------------------------------------------------
// prep2: W_hh -> i8 (row-scaled); W_ih -> bf16 (log2e-scaled, K padded 16->32)
// ---------------------------------------------------------------------------
__global__ void prep2_kernel(const float* __restrict__ W_hh, const float* __restrict__ W_ih,
                             const float* __restrict__ inv127,
                             signed char* __restrict__ w8, short* __restrict__ wih_bf) {
    const int i = blockIdx.x * blockDim.x + threadIdx.x;   // 0..65535
    if (i < G4_ * H_)
        w8[i] = (signed char)(int)rintf(W_hh[i] * inv127[i >> 7]);
    if (i < G4_ * 32) {
        const int n = i >> 5, k = i & 31;
        const float sc = (n >= 256 && n < 384) ? L2E2 : L2E;
        wih_bf[i] = (k < F_) ? f2bf(W_ih[n * F_ + k] * sc) : (short)0;
    }
}

// ---------------------------------------------------------------------------
// One timestep for both seqs; single barrier. A-tile rows 0-7 = seq0,
// 8-15 = seq1 (8x duplication). Lane (lk,lr) reg0 of colgroup (lk&1) =
// (seq lk>>1, col 32w+16(lk&1)+lr) -> 64 distinct chains, 1 per lane.
// P = parity (read h[P], write h[P^1]). PREF: next step's xacc (SX only).
// ---------------------------------------------------------------------------
template<int P, bool PREF>
__device__ __forceinline__ void lstm_step(char* lds, int tl,
    const v4i (&B8)[4][2][2], const bfrag (&Bx)[4][2],
    const float (&sw_own)[4], const float (&bias_own)[4],
    facc (&xacc)[4][2], float& cc,
    int hrd, int xrd, int wboff, bool c1)
{
    bar();
    const char* hb = lds + SH + P * 256;
    const v4i a0 = *(const v4i*)(hb + hrd);          // kslice lk   (k 16lk..)
    const v4i a1 = *(const v4i*)(hb + hrd + 128);    // kslice lk+4 (k 64+16lk)

    const v4i z4 = (v4i){0, 0, 0, 0};
    v4i acc[4][2];
#pragma unroll
    for (int q = 0; q < 4; ++q)
#pragma unroll
        for (int c = 0; c < 2; ++c)
            acc[q][c] = mfma_i8(a0, B8[q][0][c], z4);
#pragma unroll
    for (int q = 0; q < 4; ++q)
#pragma unroll
        for (int c = 0; c < 2; ++c)
            acc[q][c] = mfma_i8(a1, B8[q][1][c], acc[q][c]);

    // lane-select: colgroup lk&1, reg 0 (static indices only)
    float z[4];
#pragma unroll
    for (int q = 0; q < 4; ++q) {
        const int   ia = c1 ? acc[q][1][0] : acc[q][0][0];
        const float xa = c1 ? xacc[q][1][0] : xacc[q][0][0];
        z[q] = (float)ia * sw_own[q] + (xa + bias_own[q]);
    }

    // ---- single gate chain per lane ----
    const float ea = exp2f(-z[0]);
    const float ef = exp2f(-z[1]);
    const float eo = exp2f(-z[3]);
    const float eg = exp2f(-fabsf(z[2]));
    const float d1 = (1.0f + ea) * (1.0f + eg);
    const float d2 = 1.0f + ef;
    const float rP = __builtin_amdgcn_rcpf(d1 * d2);       // shared rcp
    const float ig = __builtin_copysignf((1.0f - eg) * (rP * d2), z[2]);
    cc = (rP * d1) * cc + ig;
    const float ec = exp2f(-L2E2 * fabsf(cc));
    const float hv = __builtin_copysignf(
        (1.0f - ec) * __builtin_amdgcn_rcpf((1.0f + eo) * (1.0f + ec)), cc);
    *(signed char*)(lds + SH + (P ^ 1) * 256 + wboff) =
        (signed char)(int)rintf(hv * 127.0f);

    if (PREF) {   // next step's x-contribution (SX-only; off the h-chain)
        const bfrag ax = *(const bfrag*)(lds + SX + (tl + 1) * 128 + xrd);
        const facc zf = (facc){0.f, 0.f, 0.f, 0.f};
#pragma unroll
        for (int q = 0; q < 4; ++q)
#pragma unroll
            for (int c = 0; c < 2; ++c)
                xacc[q][c] = __builtin_amdgcn_mfma_f32_16x16x32_bf16(ax, Bx[q][c], zf, 0, 0, 0);
    }
}

// ---------------------------------------------------------------------------
// LSTM: 448 blocks x 256 thr (4 waves); block owns 2 seqs. Wave w owns
// h-cols [32w,32w+32) as two 16-col groups across all 4 gate sections.
// 2 independent blocks/CU hide each other's serial-chain latency.
// ---------------------------------------------------------------------------
__global__ __launch_bounds__(256, 2) void lstm_kernel(
    const float* __restrict__ x,            // [B, T, N, F] fp32
    const signed char* __restrict__ w8,     // [512][128] i8
    const short* __restrict__ wih_bf,       // [512][32] bf16
    const float* __restrict__ bias,         // [512] (log2e-scaled)
    const float* __restrict__ sw,           // [512] descale * log2e
    unsigned short* __restrict__ h_out)     // [896][128] bf16
{
    const int m0  = blockIdx.x * MBLK;
    const int tid = threadIdx.x;
    const int w   = tid >> 6, l = tid & 63;
    const int lr  = l & 15, lk = l >> 4;

    __shared__ __align__(16) char lds[LDSZ];

    // ---- loop-invariant register state ----
    v4i   B8[4][2][2];                      // [gate][kslice][colgroup]
    bfrag Bx[4][2];
    float sw_own[4], bias_own[4];
    const int owncol = 32 * w + 16 * (lk & 1) + lr;
#pragma unroll
    for (int q = 0; q < 4; ++q) {
#pragma unroll
        for (int c = 0; c < 2; ++c) {
            const int n = q * 128 + 32 * w + 16 * c + lr;
#pragma unroll
            for (int ks = 0; ks < 2; ++ks)
                B8[q][ks][c] = *(const v4i*)(w8 + n * 128 + ks * 64 + lk * 16);
            Bx[q][c] = *(const bfrag*)(wih_bf + n * 32 + lk * 8);
        }
        sw_own[q]   = sw[q * 128 + owncol];
        bias_own[q] = bias[q * 128 + owncol];
    }
#pragma unroll
    for (int q = 0; q < 4; ++q) {          // pin: forbid in-loop remat
#pragma unroll
        for (int c = 0; c < 2; ++c) {
            asm volatile("" : "+v"(B8[q][0][c]));
            asm volatile("" : "+v"(B8[q][1][c]));
            asm volatile("" : "+v"(Bx[q][c]));
        }
    }

    // lane LDS offsets
    // h layout: [kslice s][group g][16B] -> addr = s*32 + g*16 (256 B/parity)
    const int hrd = lk * 32 + (lr >> 3) * 16;
    // x layout: [tl][2 seq][32k bf16] -> addr = tl*128 + g*64 + lk*16
    const int xrd = (lr >> 3) * 64 + lk * 16;
    // h write: lane owns (seq lk>>1, col owncol); kslice = owncol>>4
    const int wboff = (2 * w + (lk & 1)) * 32 + (lk >> 1) * 16 + lr;
    const bool c1 = (lk & 1) != 0;

    // staging: thread -> (tl 0..63, seq 0..1, k-half); 256 slots = 256 threads
    const int skb = tid & 1, sseq = (tid >> 1) & 1, stl = tid >> 2;
    const int seqg = m0 + sseq;
    const int bb = seqg / N_, nn = seqg % N_;
    const float* xq = x + (((size_t)bb * T_ + stl) * N_ + nn) * F_ + skb * 8;
    const int sbyte = SX + stl * 128 + sseq * 64 + skb * 16;

    // ---- init: zero LDS (x pad stays 0; h[parity 0] = initial state 0) ----
    for (int i = tid; i < LDSZ / 4; i += 256) ((int*)lds)[i] = 0;
    float4 p0 = *(const float4*)xq, p1 = *(const float4*)(xq + 4);

    float cc = 0.0f;
    facc  xacc[4][2];
    bar();

#pragma unroll 1
    for (int chunk = 0; chunk < T_ / TCH; ++chunk) {
        // stage prefetched x chunk
        {
            uint4 o;
            o.x = cvt_pk_bf16(p0.x, p0.y); o.y = cvt_pk_bf16(p0.z, p0.w);
            o.z = cvt_pk_bf16(p1.x, p1.y); o.w = cvt_pk_bf16(p1.z, p1.w);
            *(uint4*)(lds + sbyte) = o;
        }
        if (chunk + 1 < T_ / TCH) {        // next chunk loads stay in flight
            xq += TCH * N_ * F_;
            p0 = *(const float4*)xq; p1 = *(const float4*)(xq + 4);
        }
        bar();

        // preamble: xacc for tl=0
        {
            const bfrag ax = *(const bfrag*)(lds + SX + xrd);
            const facc zf = (facc){0.f, 0.f, 0.f, 0.f};
#pragma unroll
            for (int q = 0; q < 4; ++q)
#pragma unroll
                for (int c = 0; c < 2; ++c)
                    xacc[q][c] = __builtin_amdgcn_mfma_f32_16x16x32_bf16(ax, Bx[q][c], zf, 0, 0, 0);
        }

#pragma unroll 1
        for (int tl = 0; tl < TCH; tl += 2) {
            lstm_step<0, true>(lds, tl, B8, Bx, sw_own, bias_own, xacc, cc,
                               hrd, xrd, wboff, c1);
            if (tl + 2 < TCH)
                lstm_step<1, true>(lds, tl + 1, B8, Bx, sw_own, bias_own, xacc, cc,
                                   hrd, xrd, wboff, c1);
            else
                lstm_step<1, false>(lds, tl + 1, B8, Bx, sw_own, bias_own, xacc, cc,
                                    hrd, xrd, wboff, c1);
        }
    }
    bar();   // final h writes (parity 0 buf) -> readout

    // readout: h8 -> bf16 (2 seqs x 128 cols; 1 elem/thread)
    {
        const int g = tid >> 7, c = tid & 127;
        const int addr = SH + (c >> 4) * 32 + g * 16 + (c & 15);
        const signed char v = *(const signed char*)(lds + addr);
        h_out[(size_t)(m0 + g) * H_ + c] = f2bf((float)v * (1.0f / 127.0f));
    }
}

// ---------------------------------------------------------------------------
// Head kernel: one block per batch element b. GCN + linears + sigmoid.
// ---------------------------------------------------------------------------
__global__ __launch_bounds__(256) void head_kernel(
    const float* __restrict__ adj,
    const float* __restrict__ W_gcn, const float* __restrict__ b_gcn,
    const float* __restrict__ W_out, const float* __restrict__ b_out,
    const float* __restrict__ W_lin1, const float* __restrict__ b_lin1,
    const unsigned short* __restrict__ h_in,   // [896][128] bf16
    float* __restrict__ out)                   // [B, 28]
{
    const int b   = blockIdx.x;
    const int tid = threadIdx.x;

    __shared__ float s_A[N_][N_];
    __shared__ float s_d[N_];
    __shared__ float s_h[N_][H_];
    __shared__ float s_xg[N_][H_];
    __shared__ float s_g1[N_][64];
    __shared__ float s_s[N_];

    for (int idx = tid; idx < N_ * H_; idx += 256)
        s_h[idx >> 7][idx & 127] = bf2f(h_in[(size_t)b * N_ * H_ + idx]);

    if (tid < N_) {
        float sum = 0.0f;
        for (int j = 0; j < N_; ++j)
            sum += adj[tid * N_ + j] + (tid == j ? 1.0f : 0.0f);
        s_d[tid] = rsqrtf(sum);
    }
    __syncthreads();

    if (tid < N_ * N_) {
        const int i = tid / N_, j = tid % N_;
        const float a = adj[i * N_ + j] + (i == j ? 1.0f : 0.0f);
        s_A[i][j] = s_d[i] * a * s_d[j];
    }
    __syncthreads();

    for (int idx = tid; idx < N_ * H_; idx += 256) {
        const int i = idx >> 7, k = idx & 127;
        float acc = 0.0f;
#pragma unroll
        for (int j = 0; j < N_; ++j) acc += s_A[i][j] * s_h[j][k];
        s_xg[i][k] = acc;
    }
    __syncthreads();

    for (int idx = tid; idx < N_ * 64; idx += 256) {
        const int i = idx >> 6, q = idx & 63;
        float a0 = 0.f, a1 = 0.f, a2 = 0.f, a3 = 0.f;
#pragma unroll
        for (int k = 0; k < H_; k += 4) {
            a0 += s_xg[i][k+0] * W_gcn[q * H_ + k+0];
            a1 += s_xg[i][k+1] * W_gcn[q * H_ + k+1];
            a2 += s_xg[i][k+2] * W_gcn[q * H_ + k+2];
            a3 += s_xg[i][k+3] * W_gcn[q * H_ + k+3];
        }
        const float acc = b_gcn[q] + ((a0 + a1) + (a2 + a3));
        s_g1[i][q] = fmaxf(acc, 0.0f);
    }
    __syncthreads();

    if (tid < N_) {
        float acc = b_out[0];
#pragma unroll
        for (int q = 0; q < 64; ++q) acc += s_g1[tid][q] * W_out[q];
        s_s[tid] = acc;
    }
    __syncthreads();

    if (tid < 28) {
        float acc = b_lin1[tid];
#pragma unroll
        for (int i = 0; i < N_; ++i) acc += s_s[i] * W_lin1[tid * N_ + i];
        out[b * 28 + tid] = 1.0f / (1.0f + __expf(-acc));
    }
}

extern "C" void kernel_launch(void* const* d_in, const int* in_sizes, int n_in,
                              void* d_out, int out_size, void* d_ws, size_t ws_size,
                              hipStream_t stream) {
    const float* x      = (const float*)d_in[0];
    const float* adj    = (const float*)d_in[1];
    const float* W_ih   = (const float*)d_in[2];
    const float* W_hh   = (const float*)d_in[3];
    const float* b_ih   = (const float*)d_in[4];
    const float* b_hh   = (const float*)d_in[5];
    const float* W_gcn  = (const float*)d_in[6];
    const float* b_gcn  = (const float*)d_in[7];
    const float* W_out  = (const float*)d_in[8];
    const float* b_out  = (const float*)d_in[9];
    const float* W_lin1 = (const float*)d_in[10];
    const float* b_lin1 = (const float*)d_in[11];
    float* out = (float*)d_out;

    // workspace layout (bytes): total 333824
    char* ws = (char*)d_ws;
    signed char*    w8     = (signed char*)(ws);              // 512*128   =  65536
    short*          wih_bf = (short*)(ws + 65536);            // 512*32*2  =  32768
    float*          bias   = (float*)(ws + 98304);            // 512*4     =   2048
    float*          sw     = (float*)(ws + 100352);           // 512*4     =   2048
    float*          inv127 = (float*)(ws + 102400);           // 512*4     =   2048
    unsigned short* h_last = (unsigned short*)(ws + 104448);  // 896*128*2 = 229376

    prep1_kernel<<<1, 512, 0, stream>>>(W_hh, b_ih, b_hh, inv127, sw, bias);
    prep2_kernel<<<128, 512, 0, stream>>>(W_hh, W_ih, inv127, w8, wih_bf);
    lstm_kernel<<<NBLK, 256, 0, stream>>>(x, w8, wih_bf, bias, sw, h_last);
    head_kernel<<<B_, 256, 0, stream>>>(adj, W_gcn, b_gcn, W_out, b_out,
                                        W_lin1, b_lin1, h_last, out);
}

// Round 12
// 261.959 us; speedup vs baseline: 1.3006x; 1.3006x over previous
//
#include <hip/hip_runtime.h>
#include <hip/hip_bf16.h>

#define B_   64
#define T_   512
#define N_   14
#define F_   16
#define H_   128
#define G4_  512
#define TCH  64     // timesteps staged per LDS chunk
#define MBLK 4      // sequences per block (4 row-groups of 1)
#define NBLK 224

typedef __attribute__((ext_vector_type(8))) short bfrag;  // 8 bf16
typedef __attribute__((ext_vector_type(4))) float facc;   // fp32 acc
typedef __attribute__((ext_vector_type(4))) int   v4i;    // i8x16 / i32x4

#define L2E   1.4426950408889634f
#define L2E2  2.8853900817779268f

// LDS byte offsets
#define SX   0      // x: [64 tl][4 seq][32 k] bf16 (k>=16 zero) = 16 KB
#define SH   16384  // h8: [2 parity][8 kslice][4 group][16B] = 1 KB
#define LDSZ 17408

__device__ __forceinline__ short f2bf(float f) {
    unsigned u = __builtin_bit_cast(unsigned, f);
    return (short)((u + 0x7FFFu + ((u >> 16) & 1u)) >> 16);
}
__device__ __forceinline__ float bf2f(unsigned short s) {
    return __builtin_bit_cast(float, (unsigned)s << 16);
}
__device__ __forceinline__ unsigned cvt_pk_bf16(float a, float b) {
    unsigned r;
    asm("v_cvt_pk_bf16_f32 %0, %1, %2" : "=v"(r) : "v"(a), "v"(b));
    return r;
}
// i8 MFMA (validated rounds 6-11)
__device__ __forceinline__ v4i mfma_i8(v4i a, v4i b, v4i c) {
    v4i d;
    asm("v_mfma_i32_16x16x64_i8 %0, %1, %2, %3"
        : "=&v"(d) : "v"(a), "v"(b), "v"(c));
    return d;
}
// lgkm-only barrier: global prefetch loads stay in flight across barriers.
__device__ __forceinline__ void bar() {
    asm volatile("s_waitcnt lgkmcnt(0)" ::: "memory");
    __builtin_amdgcn_s_barrier();
    asm volatile("" ::: "memory");
}

// ---------------------------------------------------------------------------
// prep1: per-gate-row max of W_hh -> i8 scale; fused biases; log2e pre-scale
// (2x for the g-gate section) so the epilogue uses native exp2.
// ---------------------------------------------------------------------------
__global__ void prep1_kernel(const float* __restrict__ W_hh,
                             const float* __restrict__ b_ih, const float* __restrict__ b_hh,
                             float* __restrict__ inv127, float* __restrict__ sw,
                             float* __restrict__ bias) {
    const int g = threadIdx.x;            // 0..511
    float mx = 0.0f;
    for (int k = 0; k < H_; ++k) mx = fmaxf(mx, fabsf(W_hh[g * H_ + k]));
    const float sc = (g >= 256 && g < 384) ? L2E2 : L2E;
    inv127[g] = 127.0f / mx;
    sw[g]     = mx * sc * (1.0f / 16129.0f);   // mx/127 * 1/127 * log2e-scale
    bias[g]   = (b_ih[g] + b_hh[g]) * sc;
}

// ---------------------------------------------------------------------------
// prep2: W_hh -> i8 (row-scaled); W_ih -> bf16 (log2e-scaled, K padded 16->32)
// ---------------------------------------------------------------------------
__global__ void prep2_kernel(const float* __restrict__ W_hh, const float* __restrict__ W_ih,
                             const float* __restrict__ inv127,
                             signed char* __restrict__ w8, short* __restrict__ wih_bf) {
    const int i = blockIdx.x * blockDim.x + threadIdx.x;   // 0..65535
    if (i < G4_ * H_)
        w8[i] = (signed char)(int)rintf(W_hh[i] * inv127[i >> 7]);
    if (i < G4_ * 32) {
        const int n = i >> 5, k = i & 31;
        const float sc = (n >= 256 && n < 384) ? L2E2 : L2E;
        wih_bf[i] = (k < F_) ? f2bf(W_ih[n * F_ + k] * sc) : (short)0;
    }
}

// ---------------------------------------------------------------------------
// One timestep for ALL 4 seq-groups; single barrier. Rows 4g..4g+3 of the
// MFMA tile hold group g (duplicated); lane (lk,lr) reg 0 = (group lk, col
// hcol) -> zero-select, zero-duplication epilogue.
// Schedule: batch all 3 ds_reads; issue 8 independent i8 MFMAs + 4 x-MFMAs
// (into xacc[P^1]) under setprio(1); then the VALU/trans epilogue consumes
// xacc[P] (parity double-buffer -> no WAR hazard from the early PREF).
// ---------------------------------------------------------------------------
template<int P, bool PREF>
__device__ __forceinline__ void lstm_step(char* lds, int tl,
    const v4i (&B8)[4][2], const bfrag (&Bx)[4], const facc (&bsp)[4],
    const float (&sw4)[4], facc (&xacc)[2][4], float& cc,
    int hrd, int xrd, int wboff)
{
    bar();
    const char* hb = lds + SH + P * 512;
    const v4i a0 = *(const v4i*)(hb + hrd);          // kslice lk   (k 16lk..)
    const v4i a1 = *(const v4i*)(hb + hrd + 256);    // kslice lk+4 (k 64+16lk)
    bfrag ax;
    if (PREF) ax = *(const bfrag*)(lds + SX + (tl + 1) * 256 + xrd);

    const v4i z4 = (v4i){0, 0, 0, 0};
    v4i p[4], r[4];
    __builtin_amdgcn_s_setprio(1);
#pragma unroll
    for (int q = 0; q < 4; ++q) p[q] = mfma_i8(a0, B8[q][0], z4);
#pragma unroll
    for (int q = 0; q < 4; ++q) r[q] = mfma_i8(a1, B8[q][1], z4);
    if (PREF) {   // next step's x-part: issues while i8 MFMAs are in flight
#pragma unroll
        for (int q = 0; q < 4; ++q)
            xacc[P ^ 1][q] = __builtin_amdgcn_mfma_f32_16x16x32_bf16(ax, Bx[q], bsp[q], 0, 0, 0);
    }
    __builtin_amdgcn_s_setprio(0);

    // z[q]: reg 0 = row 4lk = group lk, col hcol. xacc[P] carries bias.
    float z[4];
#pragma unroll
    for (int q = 0; q < 4; ++q)
        z[q] = (float)(p[q][0] + r[q][0]) * sw4[q] + xacc[P][q][0];

    // ---- single gate chain per lane ----
    const float ea = exp2f(-z[0]);
    const float ef = exp2f(-z[1]);
    const float eo = exp2f(-z[3]);
    const float eg = exp2f(-fabsf(z[2]));
    const float d1 = (1.0f + ea) * (1.0f + eg);
    const float d2 = 1.0f + ef;
    const float rP = __builtin_amdgcn_rcpf(d1 * d2);       // shared rcp
    const float ig = __builtin_copysignf((1.0f - eg) * (rP * d2), z[2]);
    cc = (rP * d1) * cc + ig;
    const float ec = exp2f(-L2E2 * fabsf(cc));
    const float hv = __builtin_copysignf(
        (1.0f - ec) * __builtin_amdgcn_rcpf((1.0f + eo) * (1.0f + ec)), cc);
    *(signed char*)(lds + SH + (P ^ 1) * 512 + wboff) =
        (signed char)(int)rintf(hv * 127.0f);
}

// ---------------------------------------------------------------------------
// LSTM: 224 blocks x 512 thr; block owns 4 seqs as 4 row-groups of the tile.
// Wave w owns gate-cols {q*128 + 16w .. +16} for all gates.
// ---------------------------------------------------------------------------
__global__ __launch_bounds__(512, 2) void lstm_kernel(
    const float* __restrict__ x,            // [B, T, N, F] fp32
    const signed char* __restrict__ w8,     // [512][128] i8
    const short* __restrict__ wih_bf,       // [512][32] bf16
    const float* __restrict__ bias,         // [512] (log2e-scaled)
    const float* __restrict__ sw,           // [512] descale * log2e
    unsigned short* __restrict__ h_out)     // [896][128] bf16
{
    const int m0  = blockIdx.x * MBLK;
    const int tid = threadIdx.x;
    const int w   = tid >> 6, l = tid & 63;
    const int lr  = l & 15, lk = l >> 4;
    const int hcol = w * 16 + lr;

    __shared__ __align__(16) char lds[LDSZ];

    // ---- loop-invariant register state ----
    v4i   B8[4][2];
    bfrag Bx[4];
    facc  bsp[4];
    float sw4[4];
#pragma unroll
    for (int q = 0; q < 4; ++q) {
        const int n = q * H_ + hcol;
#pragma unroll
        for (int ks = 0; ks < 2; ++ks)
            B8[q][ks] = *(const v4i*)(w8 + n * 128 + ks * 64 + lk * 16);
        Bx[q] = *(const bfrag*)(wih_bf + n * 32 + lk * 8);
        const float b = bias[n];
        bsp[q] = (facc){b, b, b, b};
        sw4[q] = sw[n];
    }
#pragma unroll
    for (int q = 0; q < 4; ++q) {          // pin: forbid in-loop remat
        asm volatile("" : "+v"(B8[q][0]));
        asm volatile("" : "+v"(B8[q][1]));
        asm volatile("" : "+v"(Bx[q]));
        asm volatile("" : "+v"(bsp[q]));
    }

    // lane LDS offsets
    // h read (A-frag): row lr -> group lr>>2; k-slice (ks*4+lk)*16.
    //   layout: [kslice s][group][16B] -> addr = s*64 + g*16 (+ks*256 via +256)
    const int hrd = lk * 64 + (lr >> 2) * 16;
    // x read: [tl][group][32k bf16] -> addr = tl*256 + g*64 + lk*16
    const int xrd = (lr >> 2) * 64 + lk * 16;
    // h write: lane owns (group lk, col hcol); k index = hcol
    //   addr = (hcol>>4)*64 + lk*16 + (hcol&15) = w*64 + lk*16 + lr
    const int wboff = w * 64 + lk * 16 + lr;

    // staging: thread -> (tl 0..63, seq 0..3, k-half); 512 slots = 512 threads
    const int skb = tid & 1, sseq = (tid >> 1) & 3, stl = tid >> 3;
    const int seqg = m0 + sseq;
    const int bb = seqg / N_, nn = seqg % N_;
    const float* xq = x + (((size_t)bb * T_ + stl) * N_ + nn) * F_ + skb * 8;
    const int sbyte = SX + stl * 256 + sseq * 64 + skb * 16;

    // ---- init: zero LDS (x pad stays 0; h[parity 0] = initial state 0) ----
    for (int i = tid; i < LDSZ / 4; i += 512) ((int*)lds)[i] = 0;
    float4 p0 = *(const float4*)xq, p1 = *(const float4*)(xq + 4);

    float cc = 0.0f;
    facc  xacc[2][4];
    bar();

#pragma unroll 1
    for (int chunk = 0; chunk < T_ / TCH; ++chunk) {
        // stage prefetched x chunk
        {
            uint4 o;
            o.x = cvt_pk_bf16(p0.x, p0.y); o.y = cvt_pk_bf16(p0.z, p0.w);
            o.z = cvt_pk_bf16(p1.x, p1.y); o.w = cvt_pk_bf16(p1.z, p1.w);
            *(uint4*)(lds + sbyte) = o;
        }
        if (chunk + 1 < T_ / TCH) {        // next chunk loads stay in flight
            xq += TCH * N_ * F_;
            p0 = *(const float4*)xq; p1 = *(const float4*)(xq + 4);
        }
        bar();

        // preamble: xacc[0] for tl=0
        {
            const bfrag ax = *(const bfrag*)(lds + SX + xrd);
#pragma unroll
            for (int q = 0; q < 4; ++q)
                xacc[0][q] = __builtin_amdgcn_mfma_f32_16x16x32_bf16(ax, Bx[q], bsp[q], 0, 0, 0);
        }

#pragma unroll 1
        for (int tl = 0; tl < TCH; tl += 2) {
            lstm_step<0, true>(lds, tl, B8, Bx, bsp, sw4, xacc, cc,
                               hrd, xrd, wboff);
            if (tl + 2 < TCH)
                lstm_step<1, true>(lds, tl + 1, B8, Bx, bsp, sw4, xacc, cc,
                                   hrd, xrd, wboff);
            else
                lstm_step<1, false>(lds, tl + 1, B8, Bx, bsp, sw4, xacc, cc,
                                    hrd, xrd, wboff);
        }
    }
    bar();   // final h writes (parity 0 buf) -> readout

    // readout: h8 -> bf16 (4 seqs x 128 cols; 1 elem/thread)
    {
        const int g = tid >> 7, c = tid & 127;
        const int addr = SH + (c >> 4) * 64 + g * 16 + (c & 15);
        const signed char v = *(const signed char*)(lds + addr);
        h_out[(size_t)(m0 + g) * H_ + c] = f2bf((float)v * (1.0f / 127.0f));
    }
}

// ---------------------------------------------------------------------------
// Head kernel: one block per batch element b. GCN + linears + sigmoid.
// ---------------------------------------------------------------------------
__global__ __launch_bounds__(256) void head_kernel(
    const float* __restrict__ adj,
    const float* __restrict__ W_gcn, const float* __restrict__ b_gcn,
    const float* __restrict__ W_out, const float* __restrict__ b_out,
    const float* __restrict__ W_lin1, const float* __restrict__ b_lin1,
    const unsigned short* __restrict__ h_in,   // [896][128] bf16
    float* __restrict__ out)                   // [B, 28]
{
    const int b   = blockIdx.x;
    const int tid = threadIdx.x;

    __shared__ float s_A[N_][N_];
    __shared__ float s_d[N_];
    __shared__ float s_h[N_][H_];
    __shared__ float s_xg[N_][H_];
    __shared__ float s_g1[N_][64];
    __shared__ float s_s[N_];

    for (int idx = tid; idx < N_ * H_; idx += 256)
        s_h[idx >> 7][idx & 127] = bf2f(h_in[(size_t)b * N_ * H_ + idx]);

    if (tid < N_) {
        float sum = 0.0f;
        for (int j = 0; j < N_; ++j)
            sum += adj[tid * N_ + j] + (tid == j ? 1.0f : 0.0f);
        s_d[tid] = rsqrtf(sum);
    }
    __syncthreads();

    if (tid < N_ * N_) {
        const int i = tid / N_, j = tid % N_;
        const float a = adj[i * N_ + j] + (i == j ? 1.0f : 0.0f);
        s_A[i][j] = s_d[i] * a * s_d[j];
    }
    __syncthreads();

    for (int idx = tid; idx < N_ * H_; idx += 256) {
        const int i = idx >> 7, k = idx & 127;
        float acc = 0.0f;
#pragma unroll
        for (int j = 0; j < N_; ++j) acc += s_A[i][j] * s_h[j][k];
        s_xg[i][k] = acc;
    }
    __syncthreads();

    for (int idx = tid; idx < N_ * 64; idx += 256) {
        const int i = idx >> 6, q = idx & 63;
        float a0 = 0.f, a1 = 0.f, a2 = 0.f, a3 = 0.f;
#pragma unroll
        for (int k = 0; k < H_; k += 4) {
            a0 += s_xg[i][k+0] * W_gcn[q * H_ + k+0];
            a1 += s_xg[i][k+1] * W_gcn[q * H_ + k+1];
            a2 += s_xg[i][k+2] * W_gcn[q * H_ + k+2];
            a3 += s_xg[i][k+3] * W_gcn[q * H_ + k+3];
        }
        const float acc = b_gcn[q] + ((a0 + a1) + (a2 + a3));
        s_g1[i][q] = fmaxf(acc, 0.0f);
    }
    __syncthreads();

    if (tid < N_) {
        float acc = b_out[0];
#pragma unroll
        for (int q = 0; q < 64; ++q) acc += s_g1[tid][q] * W_out[q];
        s_s[tid] = acc;
    }
    __syncthreads();

    if (tid < 28) {
        float acc = b_lin1[tid];
#pragma unroll
        for (int i = 0; i < N_; ++i) acc += s_s[i] * W_lin1[tid * N_ + i];
        out[b * 28 + tid] = 1.0f / (1.0f + __expf(-acc));
    }
}

extern "C" void kernel_launch(void* const* d_in, const int* in_sizes, int n_in,
                              void* d_out, int out_size, void* d_ws, size_t ws_size,
                              hipStream_t stream) {
    const float* x      = (const float*)d_in[0];
    const float* adj    = (const float*)d_in[1];
    const float* W_ih   = (const float*)d_in[2];
    const float* W_hh   = (const float*)d_in[3];
    const float* b_ih   = (const float*)d_in[4];
    const float* b_hh   = (const float*)d_in[5];
    const float* W_gcn  = (const float*)d_in[6];
    const float* b_gcn  = (const float*)d_in[7];
    const float* W_out  = (const float*)d_in[8];
    const float* b_out  = (const float*)d_in[9];
    const float* W_lin1 = (const float*)d_in[10];
    const float* b_lin1 = (const float*)d_in[11];
    float* out = (float*)d_out;

    // workspace layout (bytes): total 333824
    char* ws = (char*)d_ws;
    signed char*    w8     = (signed char*)(ws);              // 512*128   =  65536
    short*          wih_bf = (short*)(ws + 65536);            // 512*32*2  =  32768
    float*          bias   = (float*)(ws + 98304);            // 512*4     =   2048
    float*          sw     = (float*)(ws + 100352);           // 512*4     =   2048
    float*          inv127 = (float*)(ws + 102400);           // 512*4     =   2048
    unsigned short* h_last = (unsigned short*)(ws + 104448);  // 896*128*2 = 229376

    prep1_kernel<<<1, 512, 0, stream>>>(W_hh, b_ih, b_hh, inv127, sw, bias);
    prep2_kernel<<<128, 512, 0, stream>>>(W_hh, W_ih, inv127, w8, wih_bf);
    lstm_kernel<<<NBLK, 512, 0, stream>>>(x, w8, wih_bf, bias, sw, h_last);
    head_kernel<<<B_, 256, 0, stream>>>(adj, W_gcn, b_gcn, W_out, b_out,
                                        W_lin1, b_lin1, h_last, out);
}

// Round 13
// 212.997 us; speedup vs baseline: 1.5996x; 1.2299x over previous
//
#include <hip/hip_runtime.h>
#include <hip/hip_bf16.h>

#define B_   64
#define T_   512
#define N_   14
#define F_   16
#define H_   128
#define G4_  512
#define TCH  64     // timesteps staged per LDS chunk
#define MBLK 4      // sequences per block (4 row-groups of 1)
#define NBLK 224

typedef __attribute__((ext_vector_type(8))) short bfrag;  // 8 bf16
typedef __attribute__((ext_vector_type(4))) float facc;   // fp32 acc
typedef __attribute__((ext_vector_type(4))) int   v4i;    // i8x16 / i32x4

#define L2E   1.4426950408889634f
#define L2E2  2.8853900817779268f

// LDS byte offsets
#define SX   0      // x: [64 tl][4 seq][32 k] bf16 (k>=16 zero) = 16 KB
#define SH   16384  // h8: [2 parity][8 kslice][4 group][16B] = 1 KB
#define LDSZ 17408

__device__ __forceinline__ short f2bf(float f) {
    unsigned u = __builtin_bit_cast(unsigned, f);
    return (short)((u + 0x7FFFu + ((u >> 16) & 1u)) >> 16);
}
__device__ __forceinline__ float bf2f(unsigned short s) {
    return __builtin_bit_cast(float, (unsigned)s << 16);
}
__device__ __forceinline__ unsigned cvt_pk_bf16(float a, float b) {
    unsigned r;
    asm("v_cvt_pk_bf16_f32 %0, %1, %2" : "=v"(r) : "v"(a), "v"(b));
    return r;
}
// guaranteed-native 2^-x (neg folded as input modifier; no libm expansion)
__device__ __forceinline__ float ex2n(float x) {
    float r;
    asm("v_exp_f32_e64 %0, -%1" : "=v"(r) : "v"(x));
    return r;
}
// i8 MFMA (validated rounds 6-12)
__device__ __forceinline__ v4i mfma_i8(v4i a, v4i b, v4i c) {
    v4i d;
    asm("v_mfma_i32_16x16x64_i8 %0, %1, %2, %3"
        : "=&v"(d) : "v"(a), "v"(b), "v"(c));
    return d;
}
// lgkm-only barrier: global prefetch loads stay in flight across barriers.
__device__ __forceinline__ void bar() {
    asm volatile("s_waitcnt lgkmcnt(0)" ::: "memory");
    __builtin_amdgcn_s_barrier();
    asm volatile("" ::: "memory");
}

// ---------------------------------------------------------------------------
// prep1: per-gate-row max of W_hh -> i8 scale; fused biases; log2e pre-scale
// (2x for the g-gate section) so the epilogue uses native exp2.
// ---------------------------------------------------------------------------
__global__ void prep1_kernel(const float* __restrict__ W_hh,
                             const float* __restrict__ b_ih, const float* __restrict__ b_hh,
                             float* __restrict__ inv127, float* __restrict__ sw,
                             float* __restrict__ bias) {
    const int g = threadIdx.x;            // 0..511
    float mx = 0.0f;
    for (int k = 0; k < H_; ++k) mx = fmaxf(mx, fabsf(W_hh[g * H_ + k]));
    const float sc = (g >= 256 && g < 384) ? L2E2 : L2E;
    inv127[g] = 127.0f / mx;
    sw[g]     = mx * sc * (1.0f / 16129.0f);   // mx/127 * 1/127 * log2e-scale
    bias[g]   = (b_ih[g] + b_hh[g]) * sc;
}

// ---------------------------------------------------------------------------
// prep2: W_hh -> i8 (row-scaled); W_ih -> bf16 (log2e-scaled, K padded 16->32)
// ---------------------------------------------------------------------------
__global__ void prep2_kernel(const float* __restrict__ W_hh, const float* __restrict__ W_ih,
                             const float* __restrict__ inv127,
                             signed char* __restrict__ w8, short* __restrict__ wih_bf) {
    const int i = blockIdx.x * blockDim.x + threadIdx.x;   // 0..65535
    if (i < G4_ * H_)
        w8[i] = (signed char)(int)rintf(W_hh[i] * inv127[i >> 7]);
    if (i < G4_ * 32) {
        const int n = i >> 5, k = i & 31;
        const float sc = (n >= 256 && n < 384) ? L2E2 : L2E;
        wih_bf[i] = (k < F_) ? f2bf(W_ih[n * F_ + k] * sc) : (short)0;
    }
}

// ---------------------------------------------------------------------------
// One timestep for ALL 4 seq-groups; single barrier. Rows 4g..4g+3 of the
// MFMA tile hold group g (duplicated); lane (lk,lr) reg 0 = (group lk, col
// hcol) -> zero-select, zero-duplication epilogue.
// Critical path after the barrier: 2 ds_reads -> 8 i8 MFMA -> select ->
// gate chain -> 1-byte h write. The x-read issues early (latency hidden
// under MFMA/trans) but its 4 x-MFMAs run AFTER the write, overlapping the
// barrier wait. xacc parity double-buffer -> no WAR hazard.
// ---------------------------------------------------------------------------
template<int P, bool PREF>
__device__ __forceinline__ void lstm_step(char* lds, int tl,
    const v4i (&B8)[4][2], const bfrag (&Bx)[4], const facc (&bsp)[4],
    const float (&sw4)[4], facc (&xacc)[2][4], float& cc,
    int hrd, int xrd, int wboff)
{
    bar();
    const char* hb = lds + SH + P * 512;
    const v4i a0 = *(const v4i*)(hb + hrd);          // kslice lk   (k 16lk..)
    const v4i a1 = *(const v4i*)(hb + hrd + 256);    // kslice lk+4 (k 64+16lk)
    bfrag ax;
    if (PREF) ax = *(const bfrag*)(lds + SX + (tl + 1) * 256 + xrd);

    const v4i z4 = (v4i){0, 0, 0, 0};
    v4i p[4], r[4];
    __builtin_amdgcn_s_setprio(1);
#pragma unroll
    for (int q = 0; q < 4; ++q) p[q] = mfma_i8(a0, B8[q][0], z4);
#pragma unroll
    for (int q = 0; q < 4; ++q) r[q] = mfma_i8(a1, B8[q][1], z4);
    __builtin_amdgcn_s_setprio(0);

    // z[q]: reg 0 = row 4lk = group lk, col hcol. xacc[P] carries bias.
    float z[4];
#pragma unroll
    for (int q = 0; q < 4; ++q)
        z[q] = (float)(p[q][0] + r[q][0]) * sw4[q] + xacc[P][q][0];

    // ---- single gate chain per lane (5 native exp2, 2 rcp) ----
    const float ea = ex2n(z[0]);
    const float ef = ex2n(z[1]);
    const float eo = ex2n(z[3]);
    const float eg = ex2n(fabsf(z[2]));
    const float d1 = (1.0f + ea) * (1.0f + eg);
    const float d2 = 1.0f + ef;
    const float rP = __builtin_amdgcn_rcpf(d1 * d2);       // shared rcp
    const float ig = __builtin_copysignf((1.0f - eg) * (rP * d2), z[2]);
    cc = (rP * d1) * cc + ig;
    const float ec = ex2n(L2E2 * fabsf(cc));
    const float hv = __builtin_copysignf(
        (1.0f - ec) * __builtin_amdgcn_rcpf((1.0f + eo) * (1.0f + ec)), cc);
    *(signed char*)(lds + SH + (P ^ 1) * 512 + wboff) =
        (signed char)(int)rintf(hv * 127.0f);

    if (PREF) {   // next step's x-part: overlaps the barrier wait
#pragma unroll
        for (int q = 0; q < 4; ++q)
            xacc[P ^ 1][q] = __builtin_amdgcn_mfma_f32_16x16x32_bf16(ax, Bx[q], bsp[q], 0, 0, 0);
    }
}

// ---------------------------------------------------------------------------
// LSTM: 224 blocks x 512 thr; block owns 4 seqs as 4 row-groups of the tile.
// Wave w owns gate-cols {q*128 + 16w .. +16} for all gates.
// ---------------------------------------------------------------------------
__global__ __launch_bounds__(512, 2) void lstm_kernel(
    const float* __restrict__ x,            // [B, T, N, F] fp32
    const signed char* __restrict__ w8,     // [512][128] i8
    const short* __restrict__ wih_bf,       // [512][32] bf16
    const float* __restrict__ bias,         // [512] (log2e-scaled)
    const float* __restrict__ sw,           // [512] descale * log2e
    unsigned short* __restrict__ h_out)     // [896][128] bf16
{
    const int m0  = blockIdx.x * MBLK;
    const int tid = threadIdx.x;
    const int w   = tid >> 6, l = tid & 63;
    const int lr  = l & 15, lk = l >> 4;
    const int hcol = w * 16 + lr;

    __shared__ __align__(16) char lds[LDSZ];

    // ---- loop-invariant register state ----
    v4i   B8[4][2];
    bfrag Bx[4];
    facc  bsp[4];
    float sw4[4];
#pragma unroll
    for (int q = 0; q < 4; ++q) {
        const int n = q * H_ + hcol;
#pragma unroll
        for (int ks = 0; ks < 2; ++ks)
            B8[q][ks] = *(const v4i*)(w8 + n * 128 + ks * 64 + lk * 16);
        Bx[q] = *(const bfrag*)(wih_bf + n * 32 + lk * 8);
        const float b = bias[n];
        bsp[q] = (facc){b, b, b, b};
        sw4[q] = sw[n];
    }
#pragma unroll
    for (int q = 0; q < 4; ++q) {          // pin: forbid in-loop remat
        asm volatile("" : "+v"(B8[q][0]));
        asm volatile("" : "+v"(B8[q][1]));
        asm volatile("" : "+v"(Bx[q]));
        asm volatile("" : "+v"(bsp[q]));
    }

    // lane LDS offsets
    // h read (A-frag): row lr -> group lr>>2; k-slice (ks*4+lk)*16.
    //   layout: [kslice s][group][16B] -> addr = s*64 + g*16 (+ks*256 via +256)
    const int hrd = lk * 64 + (lr >> 2) * 16;
    // x read: [tl][group][32k bf16] -> addr = tl*256 + g*64 + lk*16
    const int xrd = (lr >> 2) * 64 + lk * 16;
    // h write: lane owns (group lk, col hcol); k index = hcol
    //   addr = (hcol>>4)*64 + lk*16 + (hcol&15) = w*64 + lk*16 + lr
    const int wboff = w * 64 + lk * 16 + lr;

    // staging: thread -> (tl 0..63, seq 0..3, k-half); 512 slots = 512 threads
    const int skb = tid & 1, sseq = (tid >> 1) & 3, stl = tid >> 3;
    const int seqg = m0 + sseq;
    const int bb = seqg / N_, nn = seqg % N_;
    const float* xq = x + (((size_t)bb * T_ + stl) * N_ + nn) * F_ + skb * 8;
    const int sbyte = SX + stl * 256 + sseq * 64 + skb * 16;

    // ---- init: zero LDS (x pad stays 0; h[parity 0] = initial state 0) ----
    for (int i = tid; i < LDSZ / 4; i += 512) ((int*)lds)[i] = 0;
    float4 p0 = *(const float4*)xq, p1 = *(const float4*)(xq + 4);

    float cc = 0.0f;
    facc  xacc[2][4];
    bar();

#pragma unroll 1
    for (int chunk = 0; chunk < T_ / TCH; ++chunk) {
        // stage prefetched x chunk
        {
            uint4 o;
            o.x = cvt_pk_bf16(p0.x, p0.y); o.y = cvt_pk_bf16(p0.z, p0.w);
            o.z = cvt_pk_bf16(p1.x, p1.y); o.w = cvt_pk_bf16(p1.z, p1.w);
            *(uint4*)(lds + sbyte) = o;
        }
        if (chunk + 1 < T_ / TCH) {        // next chunk loads stay in flight
            xq += TCH * N_ * F_;
            p0 = *(const float4*)xq; p1 = *(const float4*)(xq + 4);
        }
        bar();

        // preamble: xacc[0] for tl=0
        {
            const bfrag ax = *(const bfrag*)(lds + SX + xrd);
#pragma unroll
            for (int q = 0; q < 4; ++q)
                xacc[0][q] = __builtin_amdgcn_mfma_f32_16x16x32_bf16(ax, Bx[q], bsp[q], 0, 0, 0);
        }

#pragma unroll 1
        for (int tl = 0; tl < TCH; tl += 2) {
            lstm_step<0, true>(lds, tl, B8, Bx, bsp, sw4, xacc, cc,
                               hrd, xrd, wboff);
            if (tl + 2 < TCH)
                lstm_step<1, true>(lds, tl + 1, B8, Bx, bsp, sw4, xacc, cc,
                                   hrd, xrd, wboff);
            else
                lstm_step<1, false>(lds, tl + 1, B8, Bx, bsp, sw4, xacc, cc,
                                    hrd, xrd, wboff);
        }
    }
    bar();   // final h writes (parity 0 buf) -> readout

    // readout: h8 -> bf16 (4 seqs x 128 cols; 1 elem/thread)
    {
        const int g = tid >> 7, c = tid & 127;
        const int addr = SH + (c >> 4) * 64 + g * 16 + (c & 15);
        const signed char v = *(const signed char*)(lds + addr);
        h_out[(size_t)(m0 + g) * H_ + c] = f2bf((float)v * (1.0f / 127.0f));
    }
}

// ---------------------------------------------------------------------------
// Head kernel: one block per batch element b. GCN + linears + sigmoid.
// ---------------------------------------------------------------------------
__global__ __launch_bounds__(256) void head_kernel(
    const float* __restrict__ adj,
    const float* __restrict__ W_gcn, const float* __restrict__ b_gcn,
    const float* __restrict__ W_out, const float* __restrict__ b_out,
    const float* __restrict__ W_lin1, const float* __restrict__ b_lin1,
    const unsigned short* __restrict__ h_in,   // [896][128] bf16
    float* __restrict__ out)                   // [B, 28]
{
    const int b   = blockIdx.x;
    const int tid = threadIdx.x;

    __shared__ float s_A[N_][N_];
    __shared__ float s_d[N_];
    __shared__ float s_h[N_][H_];
    __shared__ float s_xg[N_][H_];
    __shared__ float s_g1[N_][64];
    __shared__ float s_s[N_];

    for (int idx = tid; idx < N_ * H_; idx += 256)
        s_h[idx >> 7][idx & 127] = bf2f(h_in[(size_t)b * N_ * H_ + idx]);

    if (tid < N_) {
        float sum = 0.0f;
        for (int j = 0; j < N_; ++j)
            sum += adj[tid * N_ + j] + (tid == j ? 1.0f : 0.0f);
        s_d[tid] = rsqrtf(sum);
    }
    __syncthreads();

    if (tid < N_ * N_) {
        const int i = tid / N_, j = tid % N_;
        const float a = adj[i * N_ + j] + (i == j ? 1.0f : 0.0f);
        s_A[i][j] = s_d[i] * a * s_d[j];
    }
    __syncthreads();

    for (int idx = tid; idx < N_ * H_; idx += 256) {
        const int i = idx >> 7, k = idx & 127;
        float acc = 0.0f;
#pragma unroll
        for (int j = 0; j < N_; ++j) acc += s_A[i][j] * s_h[j][k];
        s_xg[i][k] = acc;
    }
    __syncthreads();

    for (int idx = tid; idx < N_ * 64; idx += 256) {
        const int i = idx >> 6, q = idx & 63;
        float a0 = 0.f, a1 = 0.f, a2 = 0.f, a3 = 0.f;
#pragma unroll
        for (int k = 0; k < H_; k += 4) {
            a0 += s_xg[i][k+0] * W_gcn[q * H_ + k+0];
            a1 += s_xg[i][k+1] * W_gcn[q * H_ + k+1];
            a2 += s_xg[i][k+2] * W_gcn[q * H_ + k+2];
            a3 += s_xg[i][k+3] * W_gcn[q * H_ + k+3];
        }
        const float acc = b_gcn[q] + ((a0 + a1) + (a2 + a3));
        s_g1[i][q] = fmaxf(acc, 0.0f);
    }
    __syncthreads();

    if (tid < N_) {
        float acc = b_out[0];
#pragma unroll
        for (int q = 0; q < 64; ++q) acc += s_g1[tid][q] * W_out[q];
        s_s[tid] = acc;
    }
    __syncthreads();

    if (tid < 28) {
        float acc = b_lin1[tid];
#pragma unroll
        for (int i = 0; i < N_; ++i) acc += s_s[i] * W_lin1[tid * N_ + i];
        out[b * 28 + tid] = 1.0f / (1.0f + __expf(-acc));
    }
}

extern "C" void kernel_launch(void* const* d_in, const int* in_sizes, int n_in,
                              void* d_out, int out_size, void* d_ws, size_t ws_size,
                              hipStream_t stream) {
    const float* x      = (const float*)d_in[0];
    const float* adj    = (const float*)d_in[1];
    const float* W_ih   = (const float*)d_in[2];
    const float* W_hh   = (const float*)d_in[3];
    const float* b_ih   = (const float*)d_in[4];
    const float* b_hh   = (const float*)d_in[5];
    const float* W_gcn  = (const float*)d_in[6];
    const float* b_gcn  = (const float*)d_in[7];
    const float* W_out  = (const float*)d_in[8];
    const float* b_out  = (const float*)d_in[9];
    const float* W_lin1 = (const float*)d_in[10];
    const float* b_lin1 = (const float*)d_in[11];
    float* out = (float*)d_out;

    // workspace layout (bytes): total 333824
    char* ws = (char*)d_ws;
    signed char*    w8     = (signed char*)(ws);              // 512*128   =  65536
    short*          wih_bf = (short*)(ws + 65536);            // 512*32*2  =  32768
    float*          bias   = (float*)(ws + 98304);            // 512*4     =   2048
    float*          sw     = (float*)(ws + 100352);           // 512*4     =   2048
    float*          inv127 = (float*)(ws + 102400);           // 512*4     =   2048
    unsigned short* h_last = (unsigned short*)(ws + 104448);  // 896*128*2 = 229376

    prep1_kernel<<<1, 512, 0, stream>>>(W_hh, b_ih, b_hh, inv127, sw, bias);
    prep2_kernel<<<128, 512, 0, stream>>>(W_hh, W_ih, inv127, w8, wih_bf);
    lstm_kernel<<<NBLK, 512, 0, stream>>>(x, w8, wih_bf, bias, sw, h_last);
    head_kernel<<<B_, 256, 0, stream>>>(adj, W_gcn, b_gcn, W_out, b_out,
                                        W_lin1, b_lin1, h_last, out);
}